// Round 5
// baseline (265.279 us; speedup 1.0000x reference)
//
#include <hip/hip_runtime.h>
#include <math.h>

#define BATCH 32768

typedef __attribute__((ext_vector_type(8))) short bf16x8;
typedef __attribute__((ext_vector_type(4))) float f32x4;

union U4 { uint4 u; bf16x8 b; };

__device__ __forceinline__ float sigmoidf_(float v) {
    return __builtin_amdgcn_rcpf(1.0f + __expf(-v));
}

// split f into bf16 hi (round-half-up) + bf16 lo (trunc residual), packing
// two elements per u32 via v_perm_b32.
__device__ __forceinline__ void split2(float f0, float f1, unsigned& hi, unsigned& lo) {
    unsigned u0 = __float_as_uint(f0), u1 = __float_as_uint(f1);
    unsigned h0 = (u0 + 0x8000u) & 0xffff0000u;
    unsigned h1 = (u1 + 0x8000u) & 0xffff0000u;
    hi = __builtin_amdgcn_perm(h1, h0, 0x07060302u);
    float r0 = f0 - __uint_as_float(h0);
    float r1 = f1 - __uint_as_float(h1);
    lo = __builtin_amdgcn_perm(__float_as_uint(r1), __float_as_uint(r0), 0x07060302u);
}

// ---------------------------------------------------------------------------
// K0: build split-bf16 B-fragments for phi_w1 / phi_w2 into scratch (d_out).
// u32 layout: w1h[4][64][4] @0, w1l @1024, w2h[2][4][64][4] @2048, w2l @4096.
// Lane l holds B[k=(l>>4)*8+j][col=nt*16+(l&15)]; u32 j2 packs (2j2, 2j2+1).
// ---------------------------------------------------------------------------
__global__ __launch_bounds__(256) void k_prep(
    const float* __restrict__ w1, const float* __restrict__ w2,
    unsigned* __restrict__ frag)
{
    const int tid = threadIdx.x;
    for (int idx = tid; idx < 1024; idx += 256) {
        const int nt = idx >> 8, lane = (idx >> 2) & 63, j2 = idx & 3;
        const int kg = lane >> 4, ln = lane & 15;
        const int k0 = kg * 8 + j2 * 2, k1 = k0 + 1;
        const int col = nt * 16 + ln;
        const float f0 = (k0 < 11) ? w1[k0 * 64 + col] : 0.0f;
        const float f1 = (k1 < 11) ? w1[k1 * 64 + col] : 0.0f;
        unsigned hi, lo;
        split2(f0, f1, hi, lo);
        frag[idx] = hi;
        frag[1024 + idx] = lo;
    }
    for (int idx = tid; idx < 2048; idx += 256) {
        const int s = idx >> 10, nt = (idx >> 8) & 3, lane = (idx >> 2) & 63, j2 = idx & 3;
        const int kg = lane >> 4, ln = lane & 15;
        const int k0 = s * 32 + kg * 8 + j2 * 2;
        const int col = nt * 16 + ln;
        const float f0 = w2[k0 * 64 + col];
        const float f1 = w2[(k0 + 1) * 64 + col];
        unsigned hi, lo;
        split2(f0, f1, hi, lo);
        frag[2048 + idx] = hi;
        frag[4096 + idx] = lo;
    }
}

// ---------------------------------------------------------------------------
// K1 fused: blocks [0,4096) = phi via split-bf16 MFMA, all per-m operands in
// LDS/registers; blocks [4096,4224) = omega MLP (fp32 VALU, SGPR weights).
// LDS: s_x[2816]f | s_t[4][16*68]f | s_res[64*20]f | s_w2[1024]uint4 = 50176 B
// ---------------------------------------------------------------------------
#define S_X   0
#define S_T   11264
#define S_RES 28672
#define S_W2  33792
#define SMEM_SZ 50176

__global__ __launch_bounds__(256, 3) void k_phi_omega(
    const float* __restrict__ reads,
    const float* __restrict__ b1, const float* __restrict__ b2,
    const unsigned* __restrict__ frag,
    const float* __restrict__ info,
    const float* __restrict__ ow1, const float* __restrict__ ob1,
    const float* __restrict__ ow2, const float* __restrict__ ob2,
    float* __restrict__ concat_T)
{
    __shared__ __align__(16) char smem[SMEM_SZ];
    const int tid = threadIdx.x;

    if (blockIdx.x < 4096) {
        // ------------------------------ phi ------------------------------
        const int wave = tid >> 6;
        const int lane = tid & 63;
        const int kg = lane >> 4;
        const int ln = lane & 15;

        float* s_xf = (float*)(smem + S_X);       // [256*11] packed
        float* s_res = (float*)(smem + S_RES);    // [64][20]
        uint4* sw2 = (uint4*)(smem + S_W2);       // w2h[0..512) w2l[512..1024)

        // stage reads (coalesced float4) + w2 fragments (coalesced uint4)
        {
            const float4* g = (const float4*)(reads + (size_t)blockIdx.x * 2816);
            float4* s = (float4*)s_xf;
            for (int i = tid; i < 704; i += 256) s[i] = g[i];
        }
        {
            const uint4* f4 = (const uint4*)frag;
            for (int i = tid; i < 1024; i += 256) sw2[i] = f4[512 + i];
        }

        // w1 fragments resident in registers (8 uint4), biases
        const uint4* f4 = (const uint4*)frag;
        U4 w1h[4], w1l[4];
#pragma unroll
        for (int nt = 0; nt < 4; ++nt) {
            w1h[nt].u = f4[nt * 64 + lane];
            w1l[nt].u = f4[256 + nt * 64 + lane];
        }
        float b1v[4], b2v[4];
#pragma unroll
        for (int nt = 0; nt < 4; ++nt) {
            b1v[nt] = b1[nt * 16 + ln];
            b2v[nt] = b2[nt * 16 + ln];
        }
        __syncthreads();

        float* s_tw = (float*)(smem + S_T) + wave * 16 * 68;

        for (int m = 0; m < 4; ++m) {
            const int row = wave * 64 + m * 16 + ln;

            // ---- x A-frag from packed LDS (conflict-free: gcd(11,32)=1) ----
            float xv[8];
#pragma unroll
            for (int j = 0; j < 8; ++j) xv[j] = 0.0f;
            if (kg == 0) {
#pragma unroll
                for (int j = 0; j < 8; ++j) xv[j] = s_xf[row * 11 + j];
            } else if (kg == 1) {
#pragma unroll
                for (int j = 0; j < 3; ++j) xv[j] = s_xf[row * 11 + 8 + j];
            }
            U4 xh, xl;
#pragma unroll
            for (int j2 = 0; j2 < 4; ++j2)
                split2(xv[2 * j2], xv[2 * j2 + 1],
                       ((unsigned*)&xh.u)[j2], ((unsigned*)&xl.u)[j2]);

            // ---- layer 1: 4 nt x 3 split-MFMAs (w1 in regs) ----
            f32x4 hacc[4];
#pragma unroll
            for (int nt = 0; nt < 4; ++nt) {
                f32x4 c = {0.f, 0.f, 0.f, 0.f};
                c = __builtin_amdgcn_mfma_f32_16x16x32_bf16(xl.b, w1h[nt].b, c, 0, 0, 0);
                c = __builtin_amdgcn_mfma_f32_16x16x32_bf16(xh.b, w1l[nt].b, c, 0, 0, 0);
                c = __builtin_amdgcn_mfma_f32_16x16x32_bf16(xh.b, w1h[nt].b, c, 0, 0, 0);
                hacc[nt] = c;
            }

            // ---- bias+relu -> per-wave LDS transpose (stride 68, 16B-aligned) ----
#pragma unroll
            for (int nt = 0; nt < 4; ++nt)
#pragma unroll
                for (int q = 0; q < 4; ++q)
                    s_tw[(kg * 4 + q) * 68 + nt * 16 + ln] = fmaxf(hacc[nt][q] + b1v[nt], 0.0f);

            // ---- layer 2: per s: h-frag from LDS, w2 frags from LDS, 12 MFMAs ----
            f32x4 acc[4];
#pragma unroll
            for (int nt = 0; nt < 4; ++nt)
                acc[nt] = (f32x4){b2v[nt], b2v[nt], b2v[nt], b2v[nt]};

#pragma unroll
            for (int s = 0; s < 2; ++s) {
                const float* hp = &s_tw[ln * 68 + s * 32 + kg * 8];
                float4 ha = *(const float4*)hp;
                float4 hb = *(const float4*)(hp + 4);
                U4 hh, hl;
                split2(ha.x, ha.y, ((unsigned*)&hh.u)[0], ((unsigned*)&hl.u)[0]);
                split2(ha.z, ha.w, ((unsigned*)&hh.u)[1], ((unsigned*)&hl.u)[1]);
                split2(hb.x, hb.y, ((unsigned*)&hh.u)[2], ((unsigned*)&hl.u)[2]);
                split2(hb.z, hb.w, ((unsigned*)&hh.u)[3], ((unsigned*)&hl.u)[3]);

                U4 wh[4], wl[4];
#pragma unroll
                for (int nt = 0; nt < 4; ++nt) {
                    wh[nt].u = sw2[(s * 4 + nt) * 64 + lane];
                    wl[nt].u = sw2[512 + (s * 4 + nt) * 64 + lane];
                }
#pragma unroll
                for (int nt = 0; nt < 4; ++nt) {
                    acc[nt] = __builtin_amdgcn_mfma_f32_16x16x32_bf16(hl.b, wh[nt].b, acc[nt], 0, 0, 0);
                    acc[nt] = __builtin_amdgcn_mfma_f32_16x16x32_bf16(hh.b, wl[nt].b, acc[nt], 0, 0, 0);
                    acc[nt] = __builtin_amdgcn_mfma_f32_16x16x32_bf16(hh.b, wh[nt].b, acc[nt], 0, 0, 0);
                }
            }

            // ---- sigmoid + segment mean (lanes l, l^16, l^32 hold the 3 partials) ----
#pragma unroll
            for (int nt = 0; nt < 4; ++nt) {
                float ssum = sigmoidf_(acc[nt][0]) + sigmoidf_(acc[nt][1])
                           + sigmoidf_(acc[nt][2]) + sigmoidf_(acc[nt][3]);
                ssum += __shfl_xor(ssum, 16);
                ssum += __shfl_xor(ssum, 32);
                if (lane < 16)
                    s_res[(nt * 16 + ln) * 20 + wave * 4 + m] = ssum * 0.0625f;
            }
        }
        __syncthreads();

        const int seg0 = blockIdx.x * 16;
        const int isRef = (seg0 < BATCH);
        const int colBase = seg0 - (isRef ? 0 : BATCH);
        for (int i = tid; i < 1024; i += 256) {
            const int sl = i & 15;
            const int jf = i >> 4;
            const int rrow = isRef ? jf : (64 + jf);
            concat_T[(size_t)rrow * BATCH + colBase + sl] = s_res[jf * 20 + sl];
        }
    } else {
        // ------------------------------ omega ----------------------------
        float* s_xo = (float*)smem;   // [256][9]
        const int ob = blockIdx.x - 4096;
        {
            const float4* g = (const float4*)(info + (size_t)ob * 256 * 9);
            float4* s = (float4*)s_xo;
            for (int i = tid; i < 576; i += 256) s[i] = g[i];
        }
        __syncthreads();

        float x[9];
#pragma unroll
        for (int k = 0; k < 9; ++k) x[k] = s_xo[tid * 9 + k];

        float h1[64];
#pragma unroll
        for (int j = 0; j < 64; ++j) h1[j] = ob1[j];
#pragma unroll
        for (int k = 0; k < 9; ++k) {
            const float xk = x[k];
#pragma unroll
            for (int j = 0; j < 64; ++j)
                h1[j] = fmaf(xk, ow1[k * 64 + j], h1[j]);
        }
#pragma unroll
        for (int j = 0; j < 64; ++j) h1[j] = fmaxf(h1[j], 0.0f);

        const int b = ob * 256 + tid;
        for (int j4 = 0; j4 < 16; ++j4) {
            float a0 = ob2[j4 * 4 + 0];
            float a1 = ob2[j4 * 4 + 1];
            float a2 = ob2[j4 * 4 + 2];
            float a3 = ob2[j4 * 4 + 3];
#pragma unroll
            for (int k = 0; k < 64; ++k) {
                const float* wr = ow2 + k * 64 + j4 * 4;
                const float hk = h1[k];
                a0 = fmaf(hk, wr[0], a0);
                a1 = fmaf(hk, wr[1], a1);
                a2 = fmaf(hk, wr[2], a2);
                a3 = fmaf(hk, wr[3], a3);
            }
            concat_T[(size_t)(128 + j4 * 4 + 0) * BATCH + b] = sigmoidf_(a0);
            concat_T[(size_t)(128 + j4 * 4 + 1) * BATCH + b] = sigmoidf_(a1);
            concat_T[(size_t)(128 + j4 * 4 + 2) * BATCH + b] = sigmoidf_(a2);
            concat_T[(size_t)(128 + j4 * 4 + 3) * BATCH + b] = sigmoidf_(a3);
        }
    }
}

// ---------------------------------------------------------------------------
// K3a: rho layer 1. Block = 64 b x 4 j-tiles (tid>>6 = jt, wave-uniform ->
// s_load weights); concat reads shared via L1 within the block (1x external
// traffic instead of 4x). Grid 512.
// ---------------------------------------------------------------------------
__global__ __launch_bounds__(256) void k_rho1(
    const float* __restrict__ concat_T,
    const float* __restrict__ w1, const float* __restrict__ b1,
    float* __restrict__ r1_T)
{
    const int tid = threadIdx.x;
    const int jt = tid >> 6;            // wave-uniform
    const int b = blockIdx.x * 64 + (tid & 63);

    float acc[32];
#pragma unroll
    for (int u = 0; u < 32; ++u) acc[u] = b1[jt * 32 + u];

#pragma unroll 4
    for (int k = 0; k < 192; ++k) {
        const float c = concat_T[(size_t)k * BATCH + b];
        const float* wr = w1 + k * 128 + jt * 32;   // uniform -> s_load
#pragma unroll
        for (int u = 0; u < 32; ++u)
            acc[u] = fmaf(c, wr[u], acc[u]);
    }
#pragma unroll
    for (int u = 0; u < 32; ++u)
        r1_T[(size_t)(jt * 32 + u) * BATCH + b] = fmaxf(acc[u], 0.0f);
}

// ---------------------------------------------------------------------------
// K3b: rho layer 2 + out MLP + calibration. 256 threads = 128 b x 2 k-halves,
// halves combined via LDS; threads<128 run the epilogue.
// ---------------------------------------------------------------------------
__global__ __launch_bounds__(256, 2) void k_rho2_out(
    const float* __restrict__ r1_T,
    const float* __restrict__ w2, const float* __restrict__ b2,
    const float* __restrict__ ow1, const float* __restrict__ ob1,
    const float* __restrict__ ow2, const float* __restrict__ ob2,
    const int* __restrict__ vtypes,
    const float* __restrict__ cw1, const float* __restrict__ cb1,
    const float* __restrict__ cw2, const float* __restrict__ cb2,
    const float* __restrict__ cw3, const float* __restrict__ cb3,
    const float* __restrict__ max_logit,
    float* __restrict__ out)
{
    __shared__ __align__(16) float s_part[128][68];     // 34.8 KB
    __shared__ __align__(16) float s_ow1[3 * 64 * 32];  // 24 KB
    __shared__ float s_ow2[96];
    __shared__ float s_ob1[96];
    __shared__ float s_ob2[3];

    const int tid = threadIdx.x;
    {
        const float4* g = (const float4*)ow1;
        float4* s = (float4*)s_ow1;
        for (int i = tid; i < 1536; i += 256) s[i] = g[i];
    }
    if (tid < 96) { s_ow2[tid] = ow2[tid]; s_ob1[tid] = ob1[tid]; }
    if (tid < 3)  { s_ob2[tid] = ob2[tid]; }

    const int bl = tid & 127;
    const int b = blockIdx.x * 128 + bl;
    const int halfu = __builtin_amdgcn_readfirstlane(tid >> 7);  // wave-uniform

    float agg[64];
    if (halfu == 0) {
#pragma unroll
        for (int m = 0; m < 64; ++m) agg[m] = b2[m];
    } else {
#pragma unroll
        for (int m = 0; m < 64; ++m) agg[m] = 0.0f;
    }
    const float* wbase = w2 + halfu * 64 * 64;
    const float* rbase = r1_T + (size_t)halfu * 64 * BATCH;
#pragma unroll 2
    for (int kk = 0; kk < 64; ++kk) {
        const float rr = rbase[(size_t)kk * BATCH + b];
        const float* wr = wbase + kk * 64;              // uniform -> s_load
#pragma unroll
        for (int m = 0; m < 64; ++m)
            agg[m] = fmaf(rr, wr[m], agg[m]);
    }

    if (tid >= 128) {
#pragma unroll
        for (int q = 0; q < 16; ++q)
            *(float4*)&s_part[bl][q * 4] = *(float4*)&agg[q * 4];
    }
    __syncthreads();
    if (tid < 128) {
#pragma unroll
        for (int q = 0; q < 16; ++q) {
            float4 p = *(const float4*)&s_part[bl][q * 4];
            agg[q * 4 + 0] += p.x;
            agg[q * 4 + 1] += p.y;
            agg[q * 4 + 2] += p.z;
            agg[q * 4 + 3] += p.w;
        }

        const int t = vtypes[b];
        float o = s_ob2[t];
        for (int j4 = 0; j4 < 8; ++j4) {
            float a0 = s_ob1[t * 32 + j4 * 4 + 0];
            float a1 = s_ob1[t * 32 + j4 * 4 + 1];
            float a2 = s_ob1[t * 32 + j4 * 4 + 2];
            float a3 = s_ob1[t * 32 + j4 * 4 + 3];
#pragma unroll
            for (int k = 0; k < 64; ++k) {
                float4 w = ((const float4*)s_ow1)[(t * 64 + k) * 8 + j4];
                const float ak = agg[k];
                a0 = fmaf(ak, w.x, a0);
                a1 = fmaf(ak, w.y, a1);
                a2 = fmaf(ak, w.z, a2);
                a3 = fmaf(ak, w.w, a3);
            }
            o += fmaxf(a0, 0.0f) * s_ow2[t * 32 + j4 * 4 + 0];
            o += fmaxf(a1, 0.0f) * s_ow2[t * 32 + j4 * 4 + 1];
            o += fmaxf(a2, 0.0f) * s_ow2[t * 32 + j4 * 4 + 2];
            o += fmaxf(a3, 0.0f) * s_ow2[t * 32 + j4 * 4 + 3];
        }

        float t1[5], t2[5];
#pragma unroll
        for (int i = 0; i < 5; ++i)
            t1[i] = fmaxf(4.0f * cw1[i] + 4.0f * cw1[5 + i] + cb1[i], 0.0f);
#pragma unroll
        for (int i = 0; i < 5; ++i) {
            float a = cb2[i];
#pragma unroll
            for (int j = 0; j < 5; ++j) a = fmaf(t1[j], cw2[j * 5 + i], a);
            t2[i] = fmaxf(a, 0.0f);
        }
        float T = cb3[0];
#pragma unroll
        for (int i = 0; i < 5; ++i) T = fmaf(t2[i], cw3[i], T);

        const float ml = max_logit[0];
        out[b] = ml * tanhf(o * T / ml);
    }
}

// ---------------------------------------------------------------------------
extern "C" void kernel_launch(void* const* d_in, const int* in_sizes, int n_in,
                              void* d_out, int out_size, void* d_ws, size_t ws_size,
                              hipStream_t stream)
{
    const float* reads   = (const float*)d_in[0];
    const float* info    = (const float*)d_in[1];
    const int*   vtypes  = (const int*)d_in[3];
    const float* phi_w1  = (const float*)d_in[4];
    const float* phi_b1  = (const float*)d_in[5];
    const float* phi_w2  = (const float*)d_in[6];
    const float* phi_b2  = (const float*)d_in[7];
    const float* om_w1   = (const float*)d_in[8];
    const float* om_b1   = (const float*)d_in[9];
    const float* om_w2   = (const float*)d_in[10];
    const float* om_b2   = (const float*)d_in[11];
    const float* rho_w1  = (const float*)d_in[12];
    const float* rho_b1  = (const float*)d_in[13];
    const float* rho_w2  = (const float*)d_in[14];
    const float* rho_b2  = (const float*)d_in[15];
    const float* out_w1  = (const float*)d_in[16];
    const float* out_b1  = (const float*)d_in[17];
    const float* out_w2  = (const float*)d_in[18];
    const float* out_b2  = (const float*)d_in[19];
    const float* cal_w1  = (const float*)d_in[20];
    const float* cal_b1  = (const float*)d_in[21];
    const float* cal_w2  = (const float*)d_in[22];
    const float* cal_b2  = (const float*)d_in[23];
    const float* cal_w3  = (const float*)d_in[24];
    const float* cal_b3  = (const float*)d_in[25];
    const float* max_lg  = (const float*)d_in[26];

    float* concat_T = (float*)d_ws;                       // [192][32768]
    float* r1_T = concat_T + (size_t)192 * BATCH;         // [128][32768]
    unsigned* frag = (unsigned*)d_out;                    // 24 KB scratch, overwritten at end

    k_prep<<<dim3(1), dim3(256), 0, stream>>>(phi_w1, phi_w2, frag);
    k_phi_omega<<<dim3(4224), dim3(256), 0, stream>>>(reads, phi_b1, phi_b2, frag,
                                                      info, om_w1, om_b1, om_w2, om_b2,
                                                      concat_T);
    k_rho1<<<dim3(512), dim3(256), 0, stream>>>(concat_T, rho_w1, rho_b1, r1_T);
    k_rho2_out<<<dim3(256), dim3(256), 0, stream>>>(r1_T, rho_w2, rho_b2,
                                                    out_w1, out_b1, out_w2, out_b2,
                                                    vtypes,
                                                    cal_w1, cal_b1, cal_w2, cal_b2, cal_w3, cal_b3,
                                                    max_lg, (float*)d_out);
}

// Round 6
// 191.814 us; speedup vs baseline: 1.3830x; 1.3830x over previous
//
#include <hip/hip_runtime.h>
#include <math.h>

#define BATCH 32768

typedef __attribute__((ext_vector_type(8))) short bf16x8;
typedef __attribute__((ext_vector_type(4))) float f32x4;
typedef __attribute__((ext_vector_type(4))) unsigned u32x4;

union U4 { u32x4 u; bf16x8 b; };

__device__ __forceinline__ float sigmoidf_(float v) {
    return __builtin_amdgcn_rcpf(1.0f + __expf(-v));
}

// split f into bf16 hi (round-half-up) + bf16 lo (trunc residual), packing
// two elements per u32 via v_perm_b32.
__device__ __forceinline__ void split2(float f0, float f1, unsigned& hi, unsigned& lo) {
    unsigned u0 = __float_as_uint(f0), u1 = __float_as_uint(f1);
    unsigned h0 = (u0 + 0x8000u) & 0xffff0000u;
    unsigned h1 = (u1 + 0x8000u) & 0xffff0000u;
    hi = __builtin_amdgcn_perm(h1, h0, 0x07060302u);
    float r0 = f0 - __uint_as_float(h0);
    float r1 = f1 - __uint_as_float(h1);
    lo = __builtin_amdgcn_perm(__float_as_uint(r1), __float_as_uint(r0), 0x07060302u);
}

// ---------------------------------------------------------------------------
// K0: build split-bf16 B-fragments for phi_w1 / phi_w2 into scratch (d_out).
// u32 layout: w1h[4][64][4] @0, w1l @1024, w2h[2][4][64][4] @2048, w2l @4096.
// Lane l holds B[k=(l>>4)*8+j][col=nt*16+(l&15)]; u32 j2 packs (2j2, 2j2+1).
// ---------------------------------------------------------------------------
__global__ __launch_bounds__(256) void k_prep(
    const float* __restrict__ w1, const float* __restrict__ w2,
    unsigned* __restrict__ frag)
{
    const int tid = threadIdx.x;
    for (int idx = tid; idx < 1024; idx += 256) {
        const int nt = idx >> 8, lane = (idx >> 2) & 63, j2 = idx & 3;
        const int kg = lane >> 4, ln = lane & 15;
        const int k0 = kg * 8 + j2 * 2, k1 = k0 + 1;
        const int col = nt * 16 + ln;
        const float f0 = (k0 < 11) ? w1[k0 * 64 + col] : 0.0f;
        const float f1 = (k1 < 11) ? w1[k1 * 64 + col] : 0.0f;
        unsigned hi, lo;
        split2(f0, f1, hi, lo);
        frag[idx] = hi;
        frag[1024 + idx] = lo;
    }
    for (int idx = tid; idx < 2048; idx += 256) {
        const int s = idx >> 10, nt = (idx >> 8) & 3, lane = (idx >> 2) & 63, j2 = idx & 3;
        const int kg = lane >> 4, ln = lane & 15;
        const int k0 = s * 32 + kg * 8 + j2 * 2;
        const int col = nt * 16 + ln;
        const float f0 = w2[k0 * 64 + col];
        const float f1 = w2[(k0 + 1) * 64 + col];
        unsigned hi, lo;
        split2(f0, f1, hi, lo);
        frag[2048 + idx] = hi;
        frag[4096 + idx] = lo;
    }
}

// ---------------------------------------------------------------------------
// K1 fused: blocks [0,4096) = phi via split-bf16 MFMA with ALL weight
// fragments pinned in registers (asm keep-alive prevents the scheduler from
// sinking the loads into the m-loop); blocks [4096,4224) = omega MLP.
// LDS: s_x[2816]f @0 | s_t[4][16*68]f @11264 | s_res[64*20]f @28672 = 33792 B
// ---------------------------------------------------------------------------
#define S_X   0
#define S_T   11264
#define S_RES 28672
#define SMEM_SZ 33792

__global__ __launch_bounds__(256, 2) void k_phi_omega(
    const float* __restrict__ reads,
    const float* __restrict__ b1, const float* __restrict__ b2,
    const unsigned* __restrict__ frag,
    const float* __restrict__ info,
    const float* __restrict__ ow1, const float* __restrict__ ob1,
    const float* __restrict__ ow2, const float* __restrict__ ob2,
    float* __restrict__ concat_T)
{
    __shared__ __align__(16) char smem[SMEM_SZ];
    const int tid = threadIdx.x;

    if (blockIdx.x < 4096) {
        // ------------------------------ phi ------------------------------
        const int wave = tid >> 6;
        const int lane = tid & 63;
        const int kg = lane >> 4;
        const int ln = lane & 15;

        float* s_xf = (float*)(smem + S_X);       // [256*11] packed
        float* s_res = (float*)(smem + S_RES);    // [64][20]

        // stage reads (coalesced float4)
        {
            const float4* g = (const float4*)(reads + (size_t)blockIdx.x * 2816);
            float4* s = (float4*)s_xf;
            for (int i = tid; i < 704; i += 256) s[i] = g[i];
        }

        // ALL weight fragments resident in registers (24 coalesced b128 loads)
        const u32x4* f4 = (const u32x4*)frag;
        U4 w1h[4], w1l[4], w2h[2][4], w2l[2][4];
#pragma unroll
        for (int nt = 0; nt < 4; ++nt) {
            w1h[nt].u = f4[nt * 64 + lane];
            w1l[nt].u = f4[256 + nt * 64 + lane];
        }
#pragma unroll
        for (int s = 0; s < 2; ++s)
#pragma unroll
            for (int nt = 0; nt < 4; ++nt) {
                w2h[s][nt].u = f4[512 + (s * 4 + nt) * 64 + lane];
                w2l[s][nt].u = f4[1024 + (s * 4 + nt) * 64 + lane];
            }
        // pin: forbid sinking/remat of the fragment loads into the m-loop
        asm volatile("" :
            "+v"(w1h[0].u), "+v"(w1h[1].u), "+v"(w1h[2].u), "+v"(w1h[3].u),
            "+v"(w1l[0].u), "+v"(w1l[1].u), "+v"(w1l[2].u), "+v"(w1l[3].u));
        asm volatile("" :
            "+v"(w2h[0][0].u), "+v"(w2h[0][1].u), "+v"(w2h[0][2].u), "+v"(w2h[0][3].u),
            "+v"(w2h[1][0].u), "+v"(w2h[1][1].u), "+v"(w2h[1][2].u), "+v"(w2h[1][3].u));
        asm volatile("" :
            "+v"(w2l[0][0].u), "+v"(w2l[0][1].u), "+v"(w2l[0][2].u), "+v"(w2l[0][3].u),
            "+v"(w2l[1][0].u), "+v"(w2l[1][1].u), "+v"(w2l[1][2].u), "+v"(w2l[1][3].u));

        float b1v[4], b2v[4];
#pragma unroll
        for (int nt = 0; nt < 4; ++nt) {
            b1v[nt] = b1[nt * 16 + ln];
            b2v[nt] = b2[nt * 16 + ln];
        }
        __syncthreads();

        float* s_tw = (float*)(smem + S_T) + wave * 16 * 68;

        for (int m = 0; m < 4; ++m) {
            const int row = wave * 64 + m * 16 + ln;

            // ---- x A-frag from packed LDS (conflict-free: gcd(11,32)=1) ----
            float xv[8];
#pragma unroll
            for (int j = 0; j < 8; ++j) xv[j] = 0.0f;
            if (kg == 0) {
#pragma unroll
                for (int j = 0; j < 8; ++j) xv[j] = s_xf[row * 11 + j];
            } else if (kg == 1) {
#pragma unroll
                for (int j = 0; j < 3; ++j) xv[j] = s_xf[row * 11 + 8 + j];
            }
            U4 xh, xl;
#pragma unroll
            for (int j2 = 0; j2 < 4; ++j2)
                split2(xv[2 * j2], xv[2 * j2 + 1],
                       ((unsigned*)&xh.u)[j2], ((unsigned*)&xl.u)[j2]);

            // ---- layer 1: 4 nt x 3 split-MFMAs (all operands in regs) ----
            f32x4 hacc[4];
#pragma unroll
            for (int nt = 0; nt < 4; ++nt) {
                f32x4 c = {0.f, 0.f, 0.f, 0.f};
                c = __builtin_amdgcn_mfma_f32_16x16x32_bf16(xl.b, w1h[nt].b, c, 0, 0, 0);
                c = __builtin_amdgcn_mfma_f32_16x16x32_bf16(xh.b, w1l[nt].b, c, 0, 0, 0);
                c = __builtin_amdgcn_mfma_f32_16x16x32_bf16(xh.b, w1h[nt].b, c, 0, 0, 0);
                hacc[nt] = c;
            }

            // ---- bias+relu -> per-wave LDS transpose (stride 68) ----
#pragma unroll
            for (int nt = 0; nt < 4; ++nt)
#pragma unroll
                for (int q = 0; q < 4; ++q)
                    s_tw[(kg * 4 + q) * 68 + nt * 16 + ln] = fmaxf(hacc[nt][q] + b1v[nt], 0.0f);

            // ---- layer 2: h-frag from LDS, w2 from regs, 24 MFMAs ----
            f32x4 acc[4];
#pragma unroll
            for (int nt = 0; nt < 4; ++nt)
                acc[nt] = (f32x4){b2v[nt], b2v[nt], b2v[nt], b2v[nt]};

#pragma unroll
            for (int s = 0; s < 2; ++s) {
                const float* hp = &s_tw[ln * 68 + s * 32 + kg * 8];
                float4 ha = *(const float4*)hp;
                float4 hb = *(const float4*)(hp + 4);
                U4 hh, hl;
                split2(ha.x, ha.y, ((unsigned*)&hh.u)[0], ((unsigned*)&hl.u)[0]);
                split2(ha.z, ha.w, ((unsigned*)&hh.u)[1], ((unsigned*)&hl.u)[1]);
                split2(hb.x, hb.y, ((unsigned*)&hh.u)[2], ((unsigned*)&hl.u)[2]);
                split2(hb.z, hb.w, ((unsigned*)&hh.u)[3], ((unsigned*)&hl.u)[3]);

#pragma unroll
                for (int nt = 0; nt < 4; ++nt) {
                    acc[nt] = __builtin_amdgcn_mfma_f32_16x16x32_bf16(hl.b, w2h[s][nt].b, acc[nt], 0, 0, 0);
                    acc[nt] = __builtin_amdgcn_mfma_f32_16x16x32_bf16(hh.b, w2l[s][nt].b, acc[nt], 0, 0, 0);
                    acc[nt] = __builtin_amdgcn_mfma_f32_16x16x32_bf16(hh.b, w2h[s][nt].b, acc[nt], 0, 0, 0);
                }
            }

            // ---- sigmoid + segment mean ----
#pragma unroll
            for (int nt = 0; nt < 4; ++nt) {
                float ssum = sigmoidf_(acc[nt][0]) + sigmoidf_(acc[nt][1])
                           + sigmoidf_(acc[nt][2]) + sigmoidf_(acc[nt][3]);
                ssum += __shfl_xor(ssum, 16);
                ssum += __shfl_xor(ssum, 32);
                if (lane < 16)
                    s_res[(nt * 16 + ln) * 20 + wave * 4 + m] = ssum * 0.0625f;
            }
        }
        __syncthreads();

        const int seg0 = blockIdx.x * 16;
        const int isRef = (seg0 < BATCH);
        const int colBase = seg0 - (isRef ? 0 : BATCH);
        for (int i = tid; i < 1024; i += 256) {
            const int sl = i & 15;
            const int jf = i >> 4;
            const int rrow = isRef ? jf : (64 + jf);
            concat_T[(size_t)rrow * BATCH + colBase + sl] = s_res[jf * 20 + sl];
        }
    } else {
        // ------------------------------ omega ----------------------------
        float* s_xo = (float*)smem;   // [256][9]
        const int ob = blockIdx.x - 4096;
        {
            const float4* g = (const float4*)(info + (size_t)ob * 256 * 9);
            float4* s = (float4*)s_xo;
            for (int i = tid; i < 576; i += 256) s[i] = g[i];
        }
        __syncthreads();

        float x[9];
#pragma unroll
        for (int k = 0; k < 9; ++k) x[k] = s_xo[tid * 9 + k];

        float h1[64];
#pragma unroll
        for (int j = 0; j < 64; ++j) h1[j] = ob1[j];
#pragma unroll
        for (int k = 0; k < 9; ++k) {
            const float xk = x[k];
#pragma unroll
            for (int j = 0; j < 64; ++j)
                h1[j] = fmaf(xk, ow1[k * 64 + j], h1[j]);
        }
#pragma unroll
        for (int j = 0; j < 64; ++j) h1[j] = fmaxf(h1[j], 0.0f);

        const int b = ob * 256 + tid;
        for (int j4 = 0; j4 < 16; ++j4) {
            float a0 = ob2[j4 * 4 + 0];
            float a1 = ob2[j4 * 4 + 1];
            float a2 = ob2[j4 * 4 + 2];
            float a3 = ob2[j4 * 4 + 3];
#pragma unroll
            for (int k = 0; k < 64; ++k) {
                const float* wr = ow2 + k * 64 + j4 * 4;
                const float hk = h1[k];
                a0 = fmaf(hk, wr[0], a0);
                a1 = fmaf(hk, wr[1], a1);
                a2 = fmaf(hk, wr[2], a2);
                a3 = fmaf(hk, wr[3], a3);
            }
            concat_T[(size_t)(128 + j4 * 4 + 0) * BATCH + b] = sigmoidf_(a0);
            concat_T[(size_t)(128 + j4 * 4 + 1) * BATCH + b] = sigmoidf_(a1);
            concat_T[(size_t)(128 + j4 * 4 + 2) * BATCH + b] = sigmoidf_(a2);
            concat_T[(size_t)(128 + j4 * 4 + 3) * BATCH + b] = sigmoidf_(a3);
        }
    }
}

// ---------------------------------------------------------------------------
// K3a: rho layer 1. Block = 64 b x 4 j-tiles; jt forced to SGPR via
// readfirstlane (tid>>6 is wave-uniform but not provably so to the compiler)
// -> weight reads go back to s_load. concat reads shared via L1.
// ---------------------------------------------------------------------------
__global__ __launch_bounds__(256) void k_rho1(
    const float* __restrict__ concat_T,
    const float* __restrict__ w1, const float* __restrict__ b1,
    float* __restrict__ r1_T)
{
    const int tid = threadIdx.x;
    const int jt = __builtin_amdgcn_readfirstlane(tid >> 6);  // SGPR, exact
    const int b = blockIdx.x * 64 + (tid & 63);

    float acc[32];
#pragma unroll
    for (int u = 0; u < 32; ++u) acc[u] = b1[jt * 32 + u];    // s_load

#pragma unroll 4
    for (int k = 0; k < 192; ++k) {
        const float c = concat_T[(size_t)k * BATCH + b];
        const float* wr = w1 + k * 128 + jt * 32;             // s_load
#pragma unroll
        for (int u = 0; u < 32; ++u)
            acc[u] = fmaf(c, wr[u], acc[u]);
    }
#pragma unroll
    for (int u = 0; u < 32; ++u)
        r1_T[(size_t)(jt * 32 + u) * BATCH + b] = fmaxf(acc[u], 0.0f);
}

// ---------------------------------------------------------------------------
// K3b: rho layer 2 + out MLP + calibration. 256 threads = 128 b x 2 k-halves,
// halves combined via LDS; threads<128 run the epilogue.
// ---------------------------------------------------------------------------
__global__ __launch_bounds__(256, 2) void k_rho2_out(
    const float* __restrict__ r1_T,
    const float* __restrict__ w2, const float* __restrict__ b2,
    const float* __restrict__ ow1, const float* __restrict__ ob1,
    const float* __restrict__ ow2, const float* __restrict__ ob2,
    const int* __restrict__ vtypes,
    const float* __restrict__ cw1, const float* __restrict__ cb1,
    const float* __restrict__ cw2, const float* __restrict__ cb2,
    const float* __restrict__ cw3, const float* __restrict__ cb3,
    const float* __restrict__ max_logit,
    float* __restrict__ out)
{
    __shared__ __align__(16) float s_part[128][68];     // 34.8 KB
    __shared__ __align__(16) float s_ow1[3 * 64 * 32];  // 24 KB
    __shared__ float s_ow2[96];
    __shared__ float s_ob1[96];
    __shared__ float s_ob2[3];

    const int tid = threadIdx.x;
    {
        const float4* g = (const float4*)ow1;
        float4* s = (float4*)s_ow1;
        for (int i = tid; i < 1536; i += 256) s[i] = g[i];
    }
    if (tid < 96) { s_ow2[tid] = ow2[tid]; s_ob1[tid] = ob1[tid]; }
    if (tid < 3)  { s_ob2[tid] = ob2[tid]; }

    const int bl = tid & 127;
    const int b = blockIdx.x * 128 + bl;
    const int halfu = __builtin_amdgcn_readfirstlane(tid >> 7);  // wave-uniform

    float agg[64];
    if (halfu == 0) {
#pragma unroll
        for (int m = 0; m < 64; ++m) agg[m] = b2[m];
    } else {
#pragma unroll
        for (int m = 0; m < 64; ++m) agg[m] = 0.0f;
    }
    const float* wbase = w2 + halfu * 64 * 64;
    const float* rbase = r1_T + (size_t)halfu * 64 * BATCH;
#pragma unroll 2
    for (int kk = 0; kk < 64; ++kk) {
        const float rr = rbase[(size_t)kk * BATCH + b];
        const float* wr = wbase + kk * 64;              // uniform -> s_load
#pragma unroll
        for (int m = 0; m < 64; ++m)
            agg[m] = fmaf(rr, wr[m], agg[m]);
    }

    if (tid >= 128) {
#pragma unroll
        for (int q = 0; q < 16; ++q)
            *(float4*)&s_part[bl][q * 4] = *(float4*)&agg[q * 4];
    }
    __syncthreads();
    if (tid < 128) {
#pragma unroll
        for (int q = 0; q < 16; ++q) {
            float4 p = *(const float4*)&s_part[bl][q * 4];
            agg[q * 4 + 0] += p.x;
            agg[q * 4 + 1] += p.y;
            agg[q * 4 + 2] += p.z;
            agg[q * 4 + 3] += p.w;
        }

        const int t = vtypes[b];
        float o = s_ob2[t];
        for (int j4 = 0; j4 < 8; ++j4) {
            float a0 = s_ob1[t * 32 + j4 * 4 + 0];
            float a1 = s_ob1[t * 32 + j4 * 4 + 1];
            float a2 = s_ob1[t * 32 + j4 * 4 + 2];
            float a3 = s_ob1[t * 32 + j4 * 4 + 3];
#pragma unroll
            for (int k = 0; k < 64; ++k) {
                float4 w = ((const float4*)s_ow1)[(t * 64 + k) * 8 + j4];
                const float ak = agg[k];
                a0 = fmaf(ak, w.x, a0);
                a1 = fmaf(ak, w.y, a1);
                a2 = fmaf(ak, w.z, a2);
                a3 = fmaf(ak, w.w, a3);
            }
            o += fmaxf(a0, 0.0f) * s_ow2[t * 32 + j4 * 4 + 0];
            o += fmaxf(a1, 0.0f) * s_ow2[t * 32 + j4 * 4 + 1];
            o += fmaxf(a2, 0.0f) * s_ow2[t * 32 + j4 * 4 + 2];
            o += fmaxf(a3, 0.0f) * s_ow2[t * 32 + j4 * 4 + 3];
        }

        float t1[5], t2[5];
#pragma unroll
        for (int i = 0; i < 5; ++i)
            t1[i] = fmaxf(4.0f * cw1[i] + 4.0f * cw1[5 + i] + cb1[i], 0.0f);
#pragma unroll
        for (int i = 0; i < 5; ++i) {
            float a = cb2[i];
#pragma unroll
            for (int j = 0; j < 5; ++j) a = fmaf(t1[j], cw2[j * 5 + i], a);
            t2[i] = fmaxf(a, 0.0f);
        }
        float T = cb3[0];
#pragma unroll
        for (int i = 0; i < 5; ++i) T = fmaf(t2[i], cw3[i], T);

        const float ml = max_logit[0];
        out[b] = ml * tanhf(o * T / ml);
    }
}

// ---------------------------------------------------------------------------
extern "C" void kernel_launch(void* const* d_in, const int* in_sizes, int n_in,
                              void* d_out, int out_size, void* d_ws, size_t ws_size,
                              hipStream_t stream)
{
    const float* reads   = (const float*)d_in[0];
    const float* info    = (const float*)d_in[1];
    const int*   vtypes  = (const int*)d_in[3];
    const float* phi_w1  = (const float*)d_in[4];
    const float* phi_b1  = (const float*)d_in[5];
    const float* phi_w2  = (const float*)d_in[6];
    const float* phi_b2  = (const float*)d_in[7];
    const float* om_w1   = (const float*)d_in[8];
    const float* om_b1   = (const float*)d_in[9];
    const float* om_w2   = (const float*)d_in[10];
    const float* om_b2   = (const float*)d_in[11];
    const float* rho_w1  = (const float*)d_in[12];
    const float* rho_b1  = (const float*)d_in[13];
    const float* rho_w2  = (const float*)d_in[14];
    const float* rho_b2  = (const float*)d_in[15];
    const float* out_w1  = (const float*)d_in[16];
    const float* out_b1  = (const float*)d_in[17];
    const float* out_w2  = (const float*)d_in[18];
    const float* out_b2  = (const float*)d_in[19];
    const float* cal_w1  = (const float*)d_in[20];
    const float* cal_b1  = (const float*)d_in[21];
    const float* cal_w2  = (const float*)d_in[22];
    const float* cal_b2  = (const float*)d_in[23];
    const float* cal_w3  = (const float*)d_in[24];
    const float* cal_b3  = (const float*)d_in[25];
    const float* max_lg  = (const float*)d_in[26];

    float* concat_T = (float*)d_ws;                       // [192][32768]
    float* r1_T = concat_T + (size_t)192 * BATCH;         // [128][32768]
    unsigned* frag = (unsigned*)d_out;                    // 24 KB scratch, overwritten at end

    k_prep<<<dim3(1), dim3(256), 0, stream>>>(phi_w1, phi_w2, frag);
    k_phi_omega<<<dim3(4224), dim3(256), 0, stream>>>(reads, phi_b1, phi_b2, frag,
                                                      info, om_w1, om_b1, om_w2, om_b2,
                                                      concat_T);
    k_rho1<<<dim3(512), dim3(256), 0, stream>>>(concat_T, rho_w1, rho_b1, r1_T);
    k_rho2_out<<<dim3(256), dim3(256), 0, stream>>>(r1_T, rho_w2, rho_b2,
                                                    out_w1, out_b1, out_w2, out_b2,
                                                    vtypes,
                                                    cal_w1, cal_b1, cal_w2, cal_b2, cal_w3, cal_b3,
                                                    max_lg, (float*)d_out);
}

// Round 7
// 147.956 us; speedup vs baseline: 1.7930x; 1.2964x over previous
//
#include <hip/hip_runtime.h>
#include <math.h>

#define BATCH 32768

typedef __attribute__((ext_vector_type(8))) short bf16x8;
typedef __attribute__((ext_vector_type(4))) float f32x4;
typedef __attribute__((ext_vector_type(4))) unsigned u32x4;

union U4 { u32x4 u; bf16x8 b; };

__device__ __forceinline__ float sigmoidf_(float v) {
    return __builtin_amdgcn_rcpf(1.0f + __expf(-v));
}

// split f into bf16 hi (round-half-up) + bf16 lo (trunc residual), packing
// two elements per u32 via v_perm_b32.
__device__ __forceinline__ void split2(float f0, float f1, unsigned& hi, unsigned& lo) {
    unsigned u0 = __float_as_uint(f0), u1 = __float_as_uint(f1);
    unsigned h0 = (u0 + 0x8000u) & 0xffff0000u;
    unsigned h1 = (u1 + 0x8000u) & 0xffff0000u;
    hi = __builtin_amdgcn_perm(h1, h0, 0x07060302u);
    float r0 = f0 - __uint_as_float(h0);
    float r1 = f1 - __uint_as_float(h1);
    lo = __builtin_amdgcn_perm(__float_as_uint(r1), __float_as_uint(r0), 0x07060302u);
}

// ---------------------------------------------------------------------------
// K0: build split-bf16 B-fragments for phi_w1 / phi_w2 into scratch (d_out).
// ---------------------------------------------------------------------------
__global__ __launch_bounds__(256) void k_prep(
    const float* __restrict__ w1, const float* __restrict__ w2,
    unsigned* __restrict__ frag)
{
    const int tid = threadIdx.x;
    for (int idx = tid; idx < 1024; idx += 256) {
        const int nt = idx >> 8, lane = (idx >> 2) & 63, j2 = idx & 3;
        const int kg = lane >> 4, ln = lane & 15;
        const int k0 = kg * 8 + j2 * 2, k1 = k0 + 1;
        const int col = nt * 16 + ln;
        const float f0 = (k0 < 11) ? w1[k0 * 64 + col] : 0.0f;
        const float f1 = (k1 < 11) ? w1[k1 * 64 + col] : 0.0f;
        unsigned hi, lo;
        split2(f0, f1, hi, lo);
        frag[idx] = hi;
        frag[1024 + idx] = lo;
    }
    for (int idx = tid; idx < 2048; idx += 256) {
        const int s = idx >> 10, nt = (idx >> 8) & 3, lane = (idx >> 2) & 63, j2 = idx & 3;
        const int kg = lane >> 4, ln = lane & 15;
        const int k0 = s * 32 + kg * 8 + j2 * 2;
        const int col = nt * 16 + ln;
        const float f0 = w2[k0 * 64 + col];
        const float f1 = w2[(k0 + 1) * 64 + col];
        unsigned hi, lo;
        split2(f0, f1, hi, lo);
        frag[2048 + idx] = hi;
        frag[4096 + idx] = lo;
    }
}

// ---------------------------------------------------------------------------
// K1 fused: blocks [0,4096) = phi via split-bf16 MFMA (unchanged from R6);
// blocks [4096,4224) = omega MLP.
// ---------------------------------------------------------------------------
#define S_X   0
#define S_T   11264
#define S_RES 28672
#define SMEM_SZ 33792

__global__ __launch_bounds__(256, 2) void k_phi_omega(
    const float* __restrict__ reads,
    const float* __restrict__ b1, const float* __restrict__ b2,
    const unsigned* __restrict__ frag,
    const float* __restrict__ info,
    const float* __restrict__ ow1, const float* __restrict__ ob1,
    const float* __restrict__ ow2, const float* __restrict__ ob2,
    float* __restrict__ concat_T)
{
    __shared__ __align__(16) char smem[SMEM_SZ];
    const int tid = threadIdx.x;

    if (blockIdx.x < 4096) {
        // ------------------------------ phi ------------------------------
        const int wave = tid >> 6;
        const int lane = tid & 63;
        const int kg = lane >> 4;
        const int ln = lane & 15;

        float* s_xf = (float*)(smem + S_X);       // [256*11] packed
        float* s_res = (float*)(smem + S_RES);    // [64][20]

        {
            const float4* g = (const float4*)(reads + (size_t)blockIdx.x * 2816);
            float4* s = (float4*)s_xf;
            for (int i = tid; i < 704; i += 256) s[i] = g[i];
        }

        const u32x4* f4 = (const u32x4*)frag;
        U4 w1h[4], w1l[4], w2h[2][4], w2l[2][4];
#pragma unroll
        for (int nt = 0; nt < 4; ++nt) {
            w1h[nt].u = f4[nt * 64 + lane];
            w1l[nt].u = f4[256 + nt * 64 + lane];
        }
#pragma unroll
        for (int s = 0; s < 2; ++s)
#pragma unroll
            for (int nt = 0; nt < 4; ++nt) {
                w2h[s][nt].u = f4[512 + (s * 4 + nt) * 64 + lane];
                w2l[s][nt].u = f4[1024 + (s * 4 + nt) * 64 + lane];
            }
        asm volatile("" :
            "+v"(w1h[0].u), "+v"(w1h[1].u), "+v"(w1h[2].u), "+v"(w1h[3].u),
            "+v"(w1l[0].u), "+v"(w1l[1].u), "+v"(w1l[2].u), "+v"(w1l[3].u));
        asm volatile("" :
            "+v"(w2h[0][0].u), "+v"(w2h[0][1].u), "+v"(w2h[0][2].u), "+v"(w2h[0][3].u),
            "+v"(w2h[1][0].u), "+v"(w2h[1][1].u), "+v"(w2h[1][2].u), "+v"(w2h[1][3].u));
        asm volatile("" :
            "+v"(w2l[0][0].u), "+v"(w2l[0][1].u), "+v"(w2l[0][2].u), "+v"(w2l[0][3].u),
            "+v"(w2l[1][0].u), "+v"(w2l[1][1].u), "+v"(w2l[1][2].u), "+v"(w2l[1][3].u));

        float b1v[4], b2v[4];
#pragma unroll
        for (int nt = 0; nt < 4; ++nt) {
            b1v[nt] = b1[nt * 16 + ln];
            b2v[nt] = b2[nt * 16 + ln];
        }
        __syncthreads();

        float* s_tw = (float*)(smem + S_T) + wave * 16 * 68;

        for (int m = 0; m < 4; ++m) {
            const int row = wave * 64 + m * 16 + ln;

            float xv[8];
#pragma unroll
            for (int j = 0; j < 8; ++j) xv[j] = 0.0f;
            if (kg == 0) {
#pragma unroll
                for (int j = 0; j < 8; ++j) xv[j] = s_xf[row * 11 + j];
            } else if (kg == 1) {
#pragma unroll
                for (int j = 0; j < 3; ++j) xv[j] = s_xf[row * 11 + 8 + j];
            }
            U4 xh, xl;
#pragma unroll
            for (int j2 = 0; j2 < 4; ++j2)
                split2(xv[2 * j2], xv[2 * j2 + 1],
                       ((unsigned*)&xh.u)[j2], ((unsigned*)&xl.u)[j2]);

            f32x4 hacc[4];
#pragma unroll
            for (int nt = 0; nt < 4; ++nt) {
                f32x4 c = {0.f, 0.f, 0.f, 0.f};
                c = __builtin_amdgcn_mfma_f32_16x16x32_bf16(xl.b, w1h[nt].b, c, 0, 0, 0);
                c = __builtin_amdgcn_mfma_f32_16x16x32_bf16(xh.b, w1l[nt].b, c, 0, 0, 0);
                c = __builtin_amdgcn_mfma_f32_16x16x32_bf16(xh.b, w1h[nt].b, c, 0, 0, 0);
                hacc[nt] = c;
            }

#pragma unroll
            for (int nt = 0; nt < 4; ++nt)
#pragma unroll
                for (int q = 0; q < 4; ++q)
                    s_tw[(kg * 4 + q) * 68 + nt * 16 + ln] = fmaxf(hacc[nt][q] + b1v[nt], 0.0f);

            f32x4 acc[4];
#pragma unroll
            for (int nt = 0; nt < 4; ++nt)
                acc[nt] = (f32x4){b2v[nt], b2v[nt], b2v[nt], b2v[nt]};

#pragma unroll
            for (int s = 0; s < 2; ++s) {
                const float* hp = &s_tw[ln * 68 + s * 32 + kg * 8];
                float4 ha = *(const float4*)hp;
                float4 hb = *(const float4*)(hp + 4);
                U4 hh, hl;
                split2(ha.x, ha.y, ((unsigned*)&hh.u)[0], ((unsigned*)&hl.u)[0]);
                split2(ha.z, ha.w, ((unsigned*)&hh.u)[1], ((unsigned*)&hl.u)[1]);
                split2(hb.x, hb.y, ((unsigned*)&hh.u)[2], ((unsigned*)&hl.u)[2]);
                split2(hb.z, hb.w, ((unsigned*)&hh.u)[3], ((unsigned*)&hl.u)[3]);

#pragma unroll
                for (int nt = 0; nt < 4; ++nt) {
                    acc[nt] = __builtin_amdgcn_mfma_f32_16x16x32_bf16(hl.b, w2h[s][nt].b, acc[nt], 0, 0, 0);
                    acc[nt] = __builtin_amdgcn_mfma_f32_16x16x32_bf16(hh.b, w2l[s][nt].b, acc[nt], 0, 0, 0);
                    acc[nt] = __builtin_amdgcn_mfma_f32_16x16x32_bf16(hh.b, w2h[s][nt].b, acc[nt], 0, 0, 0);
                }
            }

#pragma unroll
            for (int nt = 0; nt < 4; ++nt) {
                float ssum = sigmoidf_(acc[nt][0]) + sigmoidf_(acc[nt][1])
                           + sigmoidf_(acc[nt][2]) + sigmoidf_(acc[nt][3]);
                ssum += __shfl_xor(ssum, 16);
                ssum += __shfl_xor(ssum, 32);
                if (lane < 16)
                    s_res[(nt * 16 + ln) * 20 + wave * 4 + m] = ssum * 0.0625f;
            }
        }
        __syncthreads();

        const int seg0 = blockIdx.x * 16;
        const int isRef = (seg0 < BATCH);
        const int colBase = seg0 - (isRef ? 0 : BATCH);
        for (int i = tid; i < 1024; i += 256) {
            const int sl = i & 15;
            const int jf = i >> 4;
            const int rrow = isRef ? jf : (64 + jf);
            concat_T[(size_t)rrow * BATCH + colBase + sl] = s_res[jf * 20 + sl];
        }
    } else {
        // ------------------------------ omega ----------------------------
        float* s_xo = (float*)smem;   // [256][9]
        const int ob = blockIdx.x - 4096;
        {
            const float4* g = (const float4*)(info + (size_t)ob * 256 * 9);
            float4* s = (float4*)s_xo;
            for (int i = tid; i < 576; i += 256) s[i] = g[i];
        }
        __syncthreads();

        float x[9];
#pragma unroll
        for (int k = 0; k < 9; ++k) x[k] = s_xo[tid * 9 + k];

        float h1[64];
#pragma unroll
        for (int j = 0; j < 64; ++j) h1[j] = ob1[j];
#pragma unroll
        for (int k = 0; k < 9; ++k) {
            const float xk = x[k];
#pragma unroll
            for (int j = 0; j < 64; ++j)
                h1[j] = fmaf(xk, ow1[k * 64 + j], h1[j]);
        }
#pragma unroll
        for (int j = 0; j < 64; ++j) h1[j] = fmaxf(h1[j], 0.0f);

        const int b = ob * 256 + tid;
        for (int j4 = 0; j4 < 16; ++j4) {
            float a0 = ob2[j4 * 4 + 0];
            float a1 = ob2[j4 * 4 + 1];
            float a2 = ob2[j4 * 4 + 2];
            float a3 = ob2[j4 * 4 + 3];
#pragma unroll
            for (int k = 0; k < 64; ++k) {
                const float* wr = ow2 + k * 64 + j4 * 4;
                const float hk = h1[k];
                a0 = fmaf(hk, wr[0], a0);
                a1 = fmaf(hk, wr[1], a1);
                a2 = fmaf(hk, wr[2], a2);
                a3 = fmaf(hk, wr[3], a3);
            }
            concat_T[(size_t)(128 + j4 * 4 + 0) * BATCH + b] = sigmoidf_(a0);
            concat_T[(size_t)(128 + j4 * 4 + 1) * BATCH + b] = sigmoidf_(a1);
            concat_T[(size_t)(128 + j4 * 4 + 2) * BATCH + b] = sigmoidf_(a2);
            concat_T[(size_t)(128 + j4 * 4 + 3) * BATCH + b] = sigmoidf_(a3);
        }
    }
}

// ---------------------------------------------------------------------------
// K3a: rho layer 1 (unchanged from R6 — proven fast).
// ---------------------------------------------------------------------------
__global__ __launch_bounds__(256) void k_rho1(
    const float* __restrict__ concat_T,
    const float* __restrict__ w1, const float* __restrict__ b1,
    float* __restrict__ r1_T)
{
    const int tid = threadIdx.x;
    const int jt = __builtin_amdgcn_readfirstlane(tid >> 6);  // SGPR, exact
    const int b = blockIdx.x * 64 + (tid & 63);

    float acc[32];
#pragma unroll
    for (int u = 0; u < 32; ++u) acc[u] = b1[jt * 32 + u];    // s_load

#pragma unroll 4
    for (int k = 0; k < 192; ++k) {
        const float c = concat_T[(size_t)k * BATCH + b];
        const float* wr = w1 + k * 128 + jt * 32;             // s_load
#pragma unroll
        for (int u = 0; u < 32; ++u)
            acc[u] = fmaf(c, wr[u], acc[u]);
    }
#pragma unroll
    for (int u = 0; u < 32; ++u)
        r1_T[(size_t)(jt * 32 + u) * BATCH + b] = fmaxf(acc[u], 0.0f);
}

// ---------------------------------------------------------------------------
// K3b REWRITTEN: rho layer 2 + out MLP + calibration, mirroring rho1's
// structure. Block = 64 b x 4 output-quarters (wave q via readfirstlane ->
// all weights s_load). agg assembled in LDS (stride 65, conflict-free).
// Epilogue: wave q<3 computes type-q logits for all 64 b (t uniform ->
// s_load out-weights, zero divergence); final select = one <=3-way LDS read.
// ---------------------------------------------------------------------------
__global__ __launch_bounds__(256, 4) void k_rho2_out(
    const float* __restrict__ r1_T,
    const float* __restrict__ w2, const float* __restrict__ b2,
    const float* __restrict__ ow1, const float* __restrict__ ob1,
    const float* __restrict__ ow2, const float* __restrict__ ob2,
    const int* __restrict__ vtypes,
    const float* __restrict__ cw1, const float* __restrict__ cb1,
    const float* __restrict__ cw2, const float* __restrict__ cb2,
    const float* __restrict__ cw3, const float* __restrict__ cb3,
    const float* __restrict__ max_logit,
    float* __restrict__ out)
{
    __shared__ float s_agg[64 * 65];   // [bl][k], stride 65 -> conflict-free
    __shared__ float s_log[3 * 65];    // [type][bl]

    const int tid = threadIdx.x;
    const int q = __builtin_amdgcn_readfirstlane(tid >> 6);   // wave-uniform
    const int bl = tid & 63;
    const int b = blockIdx.x * 64 + bl;

    // ---- rho2: acc[16] = outputs [16q,16q+16) over all 128 k ----
    float acc[16];
#pragma unroll
    for (int u = 0; u < 16; ++u) acc[u] = b2[q * 16 + u];     // s_load

#pragma unroll 4
    for (int k = 0; k < 128; ++k) {
        const float rr = r1_T[(size_t)k * BATCH + b];         // coalesced, L1-shared x4 waves
        const float* wr = w2 + k * 64 + q * 16;               // s_load
#pragma unroll
        for (int u = 0; u < 16; ++u)
            acc[u] = fmaf(rr, wr[u], acc[u]);
    }
#pragma unroll
    for (int u = 0; u < 16; ++u)
        s_agg[bl * 65 + q * 16 + u] = acc[u];
    __syncthreads();

    // ---- out MLP: wave q (<3) computes type-q logit for its 64 b ----
    if (q < 3) {
        const float* w1t = ow1 + q * (64 * 32);               // s_load (q uniform)
        float o = ob2[q];
#pragma unroll
        for (int jt = 0; jt < 4; ++jt) {
            float h[8];
#pragma unroll
            for (int j = 0; j < 8; ++j) h[j] = ob1[q * 32 + jt * 8 + j];
#pragma unroll 8
            for (int k = 0; k < 64; ++k) {
                const float ak = s_agg[bl * 65 + k];          // conflict-free
                const float* wr = w1t + k * 32 + jt * 8;      // s_load
#pragma unroll
                for (int j = 0; j < 8; ++j)
                    h[j] = fmaf(ak, wr[j], h[j]);
            }
#pragma unroll
            for (int j = 0; j < 8; ++j)
                o = fmaf(fmaxf(h[j], 0.0f), ow2[q * 32 + jt * 8 + j], o);
        }
        s_log[q * 65 + bl] = o;
    }
    __syncthreads();

    // ---- select by variant type + calibration + tanh clamp ----
    if (tid < 64) {
        const int t = vtypes[b];
        const float o = s_log[t * 65 + bl];

        // counts are exactly 16 everywhere -> sc = [4,4]
        float t1[5], t2[5];
#pragma unroll
        for (int i = 0; i < 5; ++i)
            t1[i] = fmaxf(4.0f * cw1[i] + 4.0f * cw1[5 + i] + cb1[i], 0.0f);
#pragma unroll
        for (int i = 0; i < 5; ++i) {
            float a = cb2[i];
#pragma unroll
            for (int j = 0; j < 5; ++j) a = fmaf(t1[j], cw2[j * 5 + i], a);
            t2[i] = fmaxf(a, 0.0f);
        }
        float T = cb3[0];
#pragma unroll
        for (int i = 0; i < 5; ++i) T = fmaf(t2[i], cw3[i], T);

        const float ml = max_logit[0];
        out[b] = ml * tanhf(o * T / ml);
    }
}

// ---------------------------------------------------------------------------
extern "C" void kernel_launch(void* const* d_in, const int* in_sizes, int n_in,
                              void* d_out, int out_size, void* d_ws, size_t ws_size,
                              hipStream_t stream)
{
    const float* reads   = (const float*)d_in[0];
    const float* info    = (const float*)d_in[1];
    const int*   vtypes  = (const int*)d_in[3];
    const float* phi_w1  = (const float*)d_in[4];
    const float* phi_b1  = (const float*)d_in[5];
    const float* phi_w2  = (const float*)d_in[6];
    const float* phi_b2  = (const float*)d_in[7];
    const float* om_w1   = (const float*)d_in[8];
    const float* om_b1   = (const float*)d_in[9];
    const float* om_w2   = (const float*)d_in[10];
    const float* om_b2   = (const float*)d_in[11];
    const float* rho_w1  = (const float*)d_in[12];
    const float* rho_b1  = (const float*)d_in[13];
    const float* rho_w2  = (const float*)d_in[14];
    const float* rho_b2  = (const float*)d_in[15];
    const float* out_w1  = (const float*)d_in[16];
    const float* out_b1  = (const float*)d_in[17];
    const float* out_w2  = (const float*)d_in[18];
    const float* out_b2  = (const float*)d_in[19];
    const float* cal_w1  = (const float*)d_in[20];
    const float* cal_b1  = (const float*)d_in[21];
    const float* cal_w2  = (const float*)d_in[22];
    const float* cal_b2  = (const float*)d_in[23];
    const float* cal_w3  = (const float*)d_in[24];
    const float* cal_b3  = (const float*)d_in[25];
    const float* max_lg  = (const float*)d_in[26];

    float* concat_T = (float*)d_ws;                       // [192][32768]
    float* r1_T = concat_T + (size_t)192 * BATCH;         // [128][32768]
    unsigned* frag = (unsigned*)d_out;                    // 24 KB scratch, overwritten at end

    k_prep<<<dim3(1), dim3(256), 0, stream>>>(phi_w1, phi_w2, frag);
    k_phi_omega<<<dim3(4224), dim3(256), 0, stream>>>(reads, phi_b1, phi_b2, frag,
                                                      info, om_w1, om_b1, om_w2, om_b2,
                                                      concat_T);
    k_rho1<<<dim3(512), dim3(256), 0, stream>>>(concat_T, rho_w1, rho_b1, r1_T);
    k_rho2_out<<<dim3(512), dim3(256), 0, stream>>>(r1_T, rho_w2, rho_b2,
                                                    out_w1, out_b1, out_w2, out_b2,
                                                    vtypes,
                                                    cal_w1, cal_b1, cal_w2, cal_b2, cal_w3, cal_b3,
                                                    max_lg, (float*)d_out);
}